// Round 3
// baseline (403.935 us; speedup 1.0000x reference)
//
#include <hip/hip_runtime.h>

#define U_    128
#define DIN   10240
#define RANK  320
#define NS    32
#define NTOT  384          // 320 (t) + 32 (B) + 32 (C)

// -------------------------------------------------------------------------
// Kernel 0: transpose x[128,10240] -> xT[10240,128]. ~3 us. (control)
// -------------------------------------------------------------------------
__global__ __launch_bounds__(256) void transpose_kernel(
    const float* __restrict__ x, float* __restrict__ xT)
{
    __shared__ float tile[32][33];
    int kb = blockIdx.x * 32, ub = blockIdx.y * 32;
    int tx = threadIdx.x, ty = threadIdx.y;      // (32, 8)
#pragma unroll
    for (int i = 0; i < 32; i += 8)
        tile[ty + i][tx] = x[(size_t)(ub + ty + i) * DIN + kb + tx];
    __syncthreads();
#pragma unroll
    for (int i = 0; i < 32; i += 8)
        xT[(size_t)(kb + ty + i) * U_ + ub + tx] = tile[tx][ty + i];
}

// -------------------------------------------------------------------------
// Kernel 1: gemmA — partial[kc][n][u] = sum_{k in chunk} xT[k,u] * W[k,n].
// (R2 version, proven: LDS-staged W + uniform ds_read_b128 broadcast,
//  256-thr blocks, in-block k-half combine, 3 waves/SIMD.) UNCHANGED.
// -------------------------------------------------------------------------
template<int KCC>
__global__ __launch_bounds__(256) void gemmA_kernel(
    const float* __restrict__ xT,
    const float* __restrict__ Wd, const float* __restrict__ Wb,
    const float* __restrict__ Wc,
    float* __restrict__ partial)
{
    constexpr int KCH   = DIN / KCC;      // 160 (A-tier) / 320 (B-tier)
    constexpr int KHALF = KCH / 2;
    __shared__ float Wl[KCH][32];         // 20 KB / 40 KB

    int b  = blockIdx.x;                  // nt*KCC + kc
    int nt = b / KCC;
    int kc = b % KCC;
    int n0 = nt * 32;
    int k0 = kc * KCH;

    const float* W; int ldw, c0;
    if (nt < 10)       { W = Wd; ldw = RANK; c0 = n0; }
    else if (nt == 10) { W = Wb; ldw = NS;   c0 = 0;  }
    else               { W = Wc; ldw = NS;   c0 = 0;  }

    for (int i4 = threadIdx.x; i4 < KCH * 8; i4 += 256) {
        int r = i4 >> 3;
        int c = (i4 & 7) * 4;
        *(float4*)&Wl[r][c] =
            *(const float4*)&W[(size_t)(k0 + r) * ldw + c0 + c];
    }
    __syncthreads();

    int u    = threadIdx.x & 127;
    int half = threadIdx.x >> 7;

    float acc[32];
#pragma unroll
    for (int j = 0; j < 32; ++j) acc[j] = 0.f;

    const float* xp = xT + (size_t)(k0 + half * KHALF) * U_ + u;
    int kbase = half * KHALF;

#pragma unroll 8
    for (int k = 0; k < KHALF; ++k) {
        float xv = xp[(size_t)k * U_];                 // coalesced
        const float4* wr = (const float4*)&Wl[kbase + k][0];  // uniform bcast
#pragma unroll
        for (int j4 = 0; j4 < 8; ++j4) {
            float4 w = wr[j4];
            acc[j4 * 4 + 0] += xv * w.x;
            acc[j4 * 4 + 1] += xv * w.y;
            acc[j4 * 4 + 2] += xv * w.z;
            acc[j4 * 4 + 3] += xv * w.w;
        }
    }

    __syncthreads();
    float* comb = &Wl[0][0];
    if (half == 1) {
#pragma unroll
        for (int j = 0; j < 32; ++j) comb[j * 128 + u] = acc[j];
    }
    __syncthreads();
    if (half == 0) {
        float* out = partial + (size_t)kc * (NTOT * U_) + (size_t)n0 * U_ + u;
#pragma unroll
        for (int j = 0; j < 32; ++j)
            out[(size_t)j * U_] = acc[j] + comb[j * 128 + u];
    }
}

// -------------------------------------------------------------------------
// Kernel 2: reduce KCC k-chunk partials -> tT[320,128], B[128,32], C[128,32].
// UNCHANGED.
// -------------------------------------------------------------------------
template<int KCC>
__global__ __launch_bounds__(256) void reduce_kernel(
    const float* __restrict__ partial, float* __restrict__ tT,
    float* __restrict__ Bc, float* __restrict__ Cc)
{
    int e = blockIdx.x * 256 + threadIdx.x;      // 0..49151
    float s = 0.f;
#pragma unroll 8
    for (int kc = 0; kc < KCC; ++kc)
        s += partial[(size_t)kc * (NTOT * U_) + e];
    int n = e >> 7, u = e & 127;                 // e = n*128 + u
    if (n < RANK)            tT[e] = s;
    else if (n < RANK + NS)  Bc[u * NS + (n - RANK)] = s;
    else                     Cc[u * NS + (n - RANK - NS)] = s;
}

// -------------------------------------------------------------------------
// Kernel 3 (R3): delta + ssm FUSED.
// Phase 1 == proven R2 delta kernel (128 thr = one d-column each, u-tile 8,
// tT slice staged in LDS, Wdt coalesced); results kept on-chip:
//   dls = softplus(.), dxs = delta*x, Dxs = D*x   (LDS, 12 KB)
// Phase 2 == ssm stream for this block's own [8u x 128d] panel of h:
//   lane l reads float4 index f2*128+l of the (u,d0) row-pair -> fully
//   coalesced 2 KB per block-iter; A re-read L2-resident (16 ut share it).
// Saves the 10.5 MB delta round-trip + one launch; delta compute hides
// under stream ramp. 1280 blocks = 5/CU co-resident, 10 waves/CU.
// -------------------------------------------------------------------------
__global__ __launch_bounds__(128) void delta_ssm_kernel(
    const float* __restrict__ tT, const float* __restrict__ Wdt,
    const float* __restrict__ b_dt, const float* __restrict__ x,
    const float* __restrict__ h, const float* __restrict__ A,
    const float* __restrict__ Bc, const float* __restrict__ Cc,
    const float* __restrict__ Dvec,
    float* __restrict__ y, float* __restrict__ hnew)
{
    __shared__ float ts[RANK][8];                // 10 KB
    __shared__ float dls[8][128];                // 4 KB: delta
    __shared__ float dxs[8][128];                // 4 KB: delta*x
    __shared__ float Dxs[8][128];                // 4 KB: D*x

    int tid = threadIdx.x;
    int b   = blockIdx.x;                        // ut*80 + dt
    int dt_ = b % 80, ut = b / 80;
    int d0  = dt_ * 128;
    int d   = d0 + tid;
    int u0  = ut * 8;

    // ---- phase 1: delta tile ----
    for (int i4 = tid; i4 < RANK * 2; i4 += 128) {
        int r = i4 >> 1, c = (i4 & 1) * 4;
        *(float4*)&ts[r][c] = *(const float4*)&tT[(size_t)r * U_ + u0 + c];
    }
    __syncthreads();

    float bias = b_dt[d];
    float acc[8];
#pragma unroll
    for (int i = 0; i < 8; ++i) acc[i] = bias;

#pragma unroll 4
    for (int r = 0; r < RANK; ++r) {
        float w = Wdt[(size_t)r * DIN + d];      // coalesced 512 B / block
        const float4* tp = (const float4*)&ts[r][0];   // uniform -> bcast
        float4 t0 = tp[0], t1 = tp[1];
        acc[0] += w * t0.x; acc[1] += w * t0.y;
        acc[2] += w * t0.z; acc[3] += w * t0.w;
        acc[4] += w * t1.x; acc[5] += w * t1.y;
        acc[6] += w * t1.z; acc[7] += w * t1.w;
    }

    float Dv_ = Dvec[d];
#pragma unroll
    for (int i = 0; i < 8; ++i) {
        float z  = acc[i];
        float sp = (z > 20.f) ? z : log1pf(__expf(z));
        float xv = x[(size_t)(u0 + i) * DIN + d];      // coalesced
        dls[i][tid] = sp;
        dxs[i][tid] = sp * xv;
        Dxs[i][tid] = Dv_ * xv;
    }
    __syncthreads();

    // ---- phase 2: stream h panel [u0..u0+8) x [d0..d0+128) x 32n ----
    int n4  = tid & 7;
    int dl0 = tid >> 3;                          // 0..15
    const float4* h4 = (const float4*)h;
    const float4* A4 = (const float4*)A;
    float4*      hn4 = (float4*)hnew;

    for (int ul = 0; ul < 8; ++ul) {
        size_t base = ((size_t)(u0 + ul) * DIN + d0) * 8;
        float4 bv = ((const float4*)Bc)[(u0 + ul) * 8 + n4];
        float4 cv = ((const float4*)Cc)[(u0 + ul) * 8 + n4];
#pragma unroll
        for (int f2 = 0; f2 < 8; ++f2) {
            int dloc = f2 * 16 + dl0;
            size_t gi = base + (size_t)dloc * 8 + n4;      // = base+f2*128+tid
            float4 hv = h4[gi];
            float4 av = A4[(size_t)(d0 + dloc) * 8 + n4];  // L2-resident
            float dlt = dls[ul][dloc];                     // bcast-8, no conflict
            float dx  = dxs[ul][dloc];

            float4 hn;
            hn.x = __expf(dlt * av.x) * hv.x + dx * bv.x;
            hn.y = __expf(dlt * av.y) * hv.y + dx * bv.y;
            hn.z = __expf(dlt * av.z) * hv.z + dx * bv.z;
            hn.w = __expf(dlt * av.w) * hv.w + dx * bv.w;

            hn4[gi] = hn;

            float p = hn.x * cv.x + hn.y * cv.y + hn.z * cv.z + hn.w * cv.w;
            p += __shfl_xor(p, 4, 8);
            p += __shfl_xor(p, 2, 8);
            p += __shfl_xor(p, 1, 8);
            if (n4 == 0)
                y[(size_t)(u0 + ul) * DIN + d0 + dloc] = p + Dxs[ul][dloc];
        }
    }
}

// -------------------------------------------------------------------------
extern "C" void kernel_launch(void* const* d_in, const int* in_sizes, int n_in,
                              void* d_out, int out_size, void* d_ws, size_t ws_size,
                              hipStream_t stream)
{
    const float* x   = (const float*)d_in[0];
    const float* h   = (const float*)d_in[1];
    const float* Wd  = (const float*)d_in[2];
    const float* Wdt = (const float*)d_in[3];
    const float* bdt = (const float*)d_in[4];
    const float* Wb  = (const float*)d_in[5];
    const float* Wc  = (const float*)d_in[6];
    const float* A   = (const float*)d_in[7];
    const float* Dv  = (const float*)d_in[8];

    // Tier A (KCC=64): ws = 1310720 + 64*384*128 + 49152 = 4,505,600 floats
    // (18.0 MB).  Tier B (KCC=32): 2,932,736 floats (11.7 MB, proven fit).
    const bool big = ws_size >= (size_t)4505600 * 4;
    const size_t partial_elems = (size_t)(big ? 64 : 32) * NTOT * U_;

    float* ws      = (float*)d_ws;
    float* xT      = ws;                         // 10240*128 = 1310720
    float* partial = ws + 1310720;               // KCC*384*128
    float* tT      = partial + partial_elems;    // 320*128 = 40960
    float* Bc      = tT + 40960;                 // 128*32
    float* Cc      = Bc + 4096;                  // 128*32

    float* y    = (float*)d_out;                 // [128,10240]
    float* hnew = y + (size_t)U_ * DIN;          // [128,10240,32]

    dim3 tb(32, 8);
    transpose_kernel<<<dim3(DIN / 32, U_ / 32), tb, 0, stream>>>(x, xT);
    if (big) {
        gemmA_kernel<64><<<12 * 64, 256, 0, stream>>>(xT, Wd, Wb, Wc, partial);
        reduce_kernel<64><<<192, 256, 0, stream>>>(partial, tT, Bc, Cc);
    } else {
        gemmA_kernel<32><<<12 * 32, 256, 0, stream>>>(xT, Wd, Wb, Wc, partial);
        reduce_kernel<32><<<192, 256, 0, stream>>>(partial, tT, Bc, Cc);
    }
    delta_ssm_kernel<<<1280, 128, 0, stream>>>(tT, Wdt, bdt, x, h, A,
                                               Bc, Cc, Dv, y, hnew);
}

// Round 4
// 398.209 us; speedup vs baseline: 1.0144x; 1.0144x over previous
//
#include <hip/hip_runtime.h>

#define U_    128
#define DIN   10240
#define RANK  320
#define NS    32
#define NTOT  384          // 320 (t) + 32 (B) + 32 (C)

// -------------------------------------------------------------------------
// Kernel 0: transpose x[128,10240] -> xT[10240,128]. ~3 us. (control)
// -------------------------------------------------------------------------
__global__ __launch_bounds__(256) void transpose_kernel(
    const float* __restrict__ x, float* __restrict__ xT)
{
    __shared__ float tile[32][33];
    int kb = blockIdx.x * 32, ub = blockIdx.y * 32;
    int tx = threadIdx.x, ty = threadIdx.y;      // (32, 8)
#pragma unroll
    for (int i = 0; i < 32; i += 8)
        tile[ty + i][tx] = x[(size_t)(ub + ty + i) * DIN + kb + tx];
    __syncthreads();
#pragma unroll
    for (int i = 0; i < 32; i += 8)
        xT[(size_t)(kb + ty + i) * U_ + ub + tx] = tile[tx][ty + i];
}

// -------------------------------------------------------------------------
// Kernel 1: gemmA — partial[kc][n][u] = sum_{k in chunk} xT[k,u] * W[k,n].
// (R2 version, proven.) UNCHANGED (control).
// -------------------------------------------------------------------------
template<int KCC>
__global__ __launch_bounds__(256) void gemmA_kernel(
    const float* __restrict__ xT,
    const float* __restrict__ Wd, const float* __restrict__ Wb,
    const float* __restrict__ Wc,
    float* __restrict__ partial)
{
    constexpr int KCH   = DIN / KCC;      // 160 (A-tier) / 320 (B-tier)
    constexpr int KHALF = KCH / 2;
    __shared__ float Wl[KCH][32];         // 20 KB / 40 KB

    int b  = blockIdx.x;                  // nt*KCC + kc
    int nt = b / KCC;
    int kc = b % KCC;
    int n0 = nt * 32;
    int k0 = kc * KCH;

    const float* W; int ldw, c0;
    if (nt < 10)       { W = Wd; ldw = RANK; c0 = n0; }
    else if (nt == 10) { W = Wb; ldw = NS;   c0 = 0;  }
    else               { W = Wc; ldw = NS;   c0 = 0;  }

    for (int i4 = threadIdx.x; i4 < KCH * 8; i4 += 256) {
        int r = i4 >> 3;
        int c = (i4 & 7) * 4;
        *(float4*)&Wl[r][c] =
            *(const float4*)&W[(size_t)(k0 + r) * ldw + c0 + c];
    }
    __syncthreads();

    int u    = threadIdx.x & 127;
    int half = threadIdx.x >> 7;

    float acc[32];
#pragma unroll
    for (int j = 0; j < 32; ++j) acc[j] = 0.f;

    const float* xp = xT + (size_t)(k0 + half * KHALF) * U_ + u;
    int kbase = half * KHALF;

#pragma unroll 8
    for (int k = 0; k < KHALF; ++k) {
        float xv = xp[(size_t)k * U_];                 // coalesced
        const float4* wr = (const float4*)&Wl[kbase + k][0];  // uniform bcast
#pragma unroll
        for (int j4 = 0; j4 < 8; ++j4) {
            float4 w = wr[j4];
            acc[j4 * 4 + 0] += xv * w.x;
            acc[j4 * 4 + 1] += xv * w.y;
            acc[j4 * 4 + 2] += xv * w.z;
            acc[j4 * 4 + 3] += xv * w.w;
        }
    }

    __syncthreads();
    float* comb = &Wl[0][0];
    if (half == 1) {
#pragma unroll
        for (int j = 0; j < 32; ++j) comb[j * 128 + u] = acc[j];
    }
    __syncthreads();
    if (half == 0) {
        float* out = partial + (size_t)kc * (NTOT * U_) + (size_t)n0 * U_ + u;
#pragma unroll
        for (int j = 0; j < 32; ++j)
            out[(size_t)j * U_] = acc[j] + comb[j * 128 + u];
    }
}

// -------------------------------------------------------------------------
// Kernel 2: reduce KCC k-chunk partials -> tT[320,128], B[128,32], C[128,32].
// UNCHANGED (control).
// -------------------------------------------------------------------------
template<int KCC>
__global__ __launch_bounds__(256) void reduce_kernel(
    const float* __restrict__ partial, float* __restrict__ tT,
    float* __restrict__ Bc, float* __restrict__ Cc)
{
    int e = blockIdx.x * 256 + threadIdx.x;      // 0..49151
    float s = 0.f;
#pragma unroll 8
    for (int kc = 0; kc < KCC; ++kc)
        s += partial[(size_t)kc * (NTOT * U_) + e];
    int n = e >> 7, u = e & 127;                 // e = n*128 + u
    if (n < RANK)            tT[e] = s;
    else if (n < RANK + NS)  Bc[u * NS + (n - RANK)] = s;
    else                     Cc[u * NS + (n - RANK - NS)] = s;
}

// -------------------------------------------------------------------------
// Kernel 3 (R4): delta + ssm fused — OCCUPANCY FIX.
// R3 counters: 144.9 us, hbm 23%, VALU 14.6%, occ 26.5% -> latency-bound
// at 10 waves/CU. Fix: u-tile 8 -> 4 so LDS 22.5 -> 11.1 KB and grid
// 1280 -> 2560 (10 blocks/CU co-resident), __launch_bounds__(128,5)
// => 20 waves/CU. A-tile (ul-invariant) hoisted into 8 float4 regs:
// halves per-iter vector-mem ops in the stream loop.
// Mandatory HBM ~260 MB (h read ~45% L3-absorbed) => floor ~50 us.
// -------------------------------------------------------------------------
__global__ __launch_bounds__(128, 5) void delta_ssm_kernel(
    const float* __restrict__ tT, const float* __restrict__ Wdt,
    const float* __restrict__ b_dt, const float* __restrict__ x,
    const float* __restrict__ h, const float* __restrict__ A,
    const float* __restrict__ Bc, const float* __restrict__ Cc,
    const float* __restrict__ Dvec,
    float* __restrict__ y, float* __restrict__ hnew)
{
    __shared__ float ts[RANK][4];                // 5.1 KB
    __shared__ float dls[4][128];                // 2 KB: delta
    __shared__ float dxs[4][128];                // 2 KB: delta*x
    __shared__ float Dxs[4][128];                // 2 KB: D*x

    int tid = threadIdx.x;
    int b   = blockIdx.x;                        // ut*80 + dt
    int dt_ = b % 80, ut = b / 80;
    int d0  = dt_ * 128;
    int d   = d0 + tid;
    int u0  = ut * 4;

    // ---- phase 1: delta tile (proven R2 pattern, u-tile 4) ----
    for (int r = tid; r < RANK; r += 128)        // 16B granules, L2/L3-hit
        *(float4*)&ts[r][0] = *(const float4*)&tT[(size_t)r * U_ + u0];
    __syncthreads();

    float bias = b_dt[d];
    float a0 = bias, a1 = bias, a2 = bias, a3 = bias;
#pragma unroll 4
    for (int r = 0; r < RANK; ++r) {
        float w = Wdt[(size_t)r * DIN + d];      // coalesced 512 B / block
        float4 t0 = *(const float4*)&ts[r][0];   // uniform -> bcast
        a0 += w * t0.x; a1 += w * t0.y;
        a2 += w * t0.z; a3 += w * t0.w;
    }

    float accv[4] = {a0, a1, a2, a3};
    float Dv_ = Dvec[d];
#pragma unroll
    for (int i = 0; i < 4; ++i) {
        float z  = accv[i];
        float sp = (z > 20.f) ? z : log1pf(__expf(z));
        float xv = x[(size_t)(u0 + i) * DIN + d];      // coalesced
        dls[i][tid] = sp;
        dxs[i][tid] = sp * xv;
        Dxs[i][tid] = Dv_ * xv;
    }
    __syncthreads();

    // ---- phase 2: stream h panel [u0..u0+4) x [d0..d0+128) x 32n ----
    int n4  = tid & 7;
    int dl0 = tid >> 3;                          // 0..15
    const float4* h4 = (const float4*)h;
    const float4* A4 = (const float4*)A;
    float4*      hn4 = (float4*)hnew;

    float4 av[8];                                // ul-invariant: hoist once
#pragma unroll
    for (int f2 = 0; f2 < 8; ++f2)
        av[f2] = A4[(size_t)d0 * 8 + f2 * 128 + tid];   // coalesced, L2-hit

    for (int ul = 0; ul < 4; ++ul) {
        size_t base = ((size_t)(u0 + ul) * DIN + d0) * 8;
        float4 bv = ((const float4*)Bc)[(u0 + ul) * 8 + n4];
        float4 cv = ((const float4*)Cc)[(u0 + ul) * 8 + n4];
#pragma unroll
        for (int f2 = 0; f2 < 8; ++f2) {
            int dloc = f2 * 16 + dl0;
            size_t gi = base + (size_t)f2 * 128 + tid;   // coalesced 2 KB
            float4 hv = h4[gi];
            float4 a  = av[f2];
            float dlt = dls[ul][dloc];                   // bcast-8
            float dx  = dxs[ul][dloc];

            float4 hn;
            hn.x = __expf(dlt * a.x) * hv.x + dx * bv.x;
            hn.y = __expf(dlt * a.y) * hv.y + dx * bv.y;
            hn.z = __expf(dlt * a.z) * hv.z + dx * bv.z;
            hn.w = __expf(dlt * a.w) * hv.w + dx * bv.w;

            hn4[gi] = hn;

            float p = hn.x * cv.x + hn.y * cv.y + hn.z * cv.z + hn.w * cv.w;
            p += __shfl_xor(p, 4, 8);
            p += __shfl_xor(p, 2, 8);
            p += __shfl_xor(p, 1, 8);
            if (n4 == 0)
                y[(size_t)(u0 + ul) * DIN + d0 + dloc] = p + Dxs[ul][dloc];
        }
    }
}

// -------------------------------------------------------------------------
extern "C" void kernel_launch(void* const* d_in, const int* in_sizes, int n_in,
                              void* d_out, int out_size, void* d_ws, size_t ws_size,
                              hipStream_t stream)
{
    const float* x   = (const float*)d_in[0];
    const float* h   = (const float*)d_in[1];
    const float* Wd  = (const float*)d_in[2];
    const float* Wdt = (const float*)d_in[3];
    const float* bdt = (const float*)d_in[4];
    const float* Wb  = (const float*)d_in[5];
    const float* Wc  = (const float*)d_in[6];
    const float* A   = (const float*)d_in[7];
    const float* Dv  = (const float*)d_in[8];

    // Tier A (KCC=64): ws = 1310720 + 64*384*128 + 49152 = 4,505,600 floats
    // (18.0 MB).  Tier B (KCC=32): 2,932,736 floats (11.7 MB, proven fit).
    const bool big = ws_size >= (size_t)4505600 * 4;
    const size_t partial_elems = (size_t)(big ? 64 : 32) * NTOT * U_;

    float* ws      = (float*)d_ws;
    float* xT      = ws;                         // 10240*128 = 1310720
    float* partial = ws + 1310720;               // KCC*384*128
    float* tT      = partial + partial_elems;    // 320*128 = 40960
    float* Bc      = tT + 40960;                 // 128*32
    float* Cc      = Bc + 4096;                  // 128*32

    float* y    = (float*)d_out;                 // [128,10240]
    float* hnew = y + (size_t)U_ * DIN;          // [128,10240,32]

    dim3 tb(32, 8);
    transpose_kernel<<<dim3(DIN / 32, U_ / 32), tb, 0, stream>>>(x, xT);
    if (big) {
        gemmA_kernel<64><<<12 * 64, 256, 0, stream>>>(xT, Wd, Wb, Wc, partial);
        reduce_kernel<64><<<192, 256, 0, stream>>>(partial, tT, Bc, Cc);
    } else {
        gemmA_kernel<32><<<12 * 32, 256, 0, stream>>>(xT, Wd, Wb, Wc, partial);
        reduce_kernel<32><<<192, 256, 0, stream>>>(partial, tT, Bc, Cc);
    }
    delta_ssm_kernel<<<2560, 128, 0, stream>>>(tT, Wdt, bdt, x, h, A,
                                               Bc, Cc, Dv, y, hnew);
}